// Round 1
// baseline (452.066 us; speedup 1.0000x reference)
//
#include <hip/hip_runtime.h>
#include <hip/hip_bf16.h>
#include <stdint.h>

#define N_ENC 2048
#define BATCH 32
#define M_TOT (N_ENC * BATCH)   // 65536 rows (s*32+b)
#define K_DIM 1024
#define N_DIM 1024
#define BM 128
#define BN 128
#define BK 64

typedef __attribute__((ext_vector_type(4))) float f32x4;
typedef __attribute__((ext_vector_type(8))) short short8;

__device__ __forceinline__ unsigned int pack_bf16x2(float lo, float hi) {
  unsigned int a = __float_as_uint(lo);
  unsigned int b = __float_as_uint(hi);
  a = (a + 0x7fffu + ((a >> 16) & 1u)) >> 16;          // RNE to bf16, low half
  b = (b + 0x7fffu + ((b >> 16) & 1u)) & 0xffff0000u;  // RNE to bf16, high half
  return a | b;
}

__device__ __forceinline__ float tanh_fast(float x) {
  // tanh(x) = 1 - 2/(e^{2x}+1); safe at both extremes (e->0 => -1, e->inf => 1)
  float e = __expf(2.0f * x);
  return 1.0f - 2.0f / (e + 1.0f);
}

// ---- w_enc f32 -> bf16 ----
__global__ void k_convert_bf16(const float* __restrict__ src,
                               unsigned short* __restrict__ dst, int n8) {
  int i = blockIdx.x * 256 + threadIdx.x;
  if (i >= n8) return;
  const float* p = src + (size_t)i * 8;
  f32x4 v0 = *(const f32x4*)p;
  f32x4 v1 = *(const f32x4*)(p + 4);
  uint4 o;
  o.x = pack_bf16x2(v0.x, v0.y);
  o.y = pack_bf16x2(v0.z, v0.w);
  o.z = pack_bf16x2(v1.x, v1.y);
  o.w = pack_bf16x2(v1.z, v1.w);
  *(uint4*)(dst + (size_t)i * 8) = o;
}

// ---- proj_dec[b][h] = sum_d dec[b][d] * w_dec[h][d]  (f32, tiny) ----
__global__ void k_proj_dec(const float* __restrict__ dec,
                           const float* __restrict__ w_dec,
                           float* __restrict__ proj) {
  int t = threadIdx.x;
  int hh = t & 7, b = t >> 3;          // 8 h x 32 b per block
  int h = blockIdx.x * 8 + hh;
  const float* wr = w_dec + (size_t)h * K_DIM;
  const float* dr = dec + (size_t)b * K_DIM;
  float acc = 0.f;
  for (int d = 0; d < K_DIM; d += 4) {
    f32x4 wv = *(const f32x4*)(wr + d);
    f32x4 dv = *(const f32x4*)(dr + d);
    acc = fmaf(wv.x, dv.x, acc);
    acc = fmaf(wv.y, dv.y, acc);
    acc = fmaf(wv.z, dv.z, acc);
    acc = fmaf(wv.w, dv.w, acc);
  }
  proj[b * N_DIM + h] = acc;
}

// ---- fused GEMM: logits[m] += sum_h tanh(A[m].Wenc[h] + pdec[m%32][h]) * wout[h] ----
__global__ __launch_bounds__(256) void k_gemm_fused(
    const float* __restrict__ A,           // enc_states [65536][1024] f32
    const unsigned short* __restrict__ B,  // w_enc bf16 [1024][1024]
    const float* __restrict__ pdec,        // [32][1024]
    const float* __restrict__ wout,        // [1024]
    float* __restrict__ logits)            // [65536] (pre-zeroed)
{
  __shared__ __align__(16) unsigned short Asm[BM * BK];  // 16 KiB, XOR-swizzled
  __shared__ __align__(16) unsigned short Bsm[BN * BK];  // 16 KiB, XOR-swizzled

  const int bid = blockIdx.x;
  const int nt = bid & 7;        // n fastest: 8 siblings share an A tile
  const int mt = bid >> 3;
  const int m0 = mt * BM, n0 = nt * BN;
  const int t = threadIdx.x;
  const int lane = t & 63;
  const int w = t >> 6;
  const int wm = w >> 1, wn = w & 1;     // 2x2 waves of 64x64
  const int g = lane >> 4, c16 = lane & 15;

  const f32x4 zero = {0.f, 0.f, 0.f, 0.f};
  f32x4 acc[4][4];
#pragma unroll
  for (int a = 0; a < 4; ++a)
#pragma unroll
    for (int b = 0; b < 4; ++b) acc[a][b] = zero;

  for (int kt = 0; kt < K_DIM / BK; ++kt) {
    const int k0 = kt * BK;
    // -- stage A: global f32 -> regs -> bf16 -> swizzled LDS --
#pragma unroll
    for (int i = 0; i < 4; ++i) {
      int item = i * 256 + t;      // 1024 items of 8 f32
      int row = item >> 3;         // 0..127
      int sub = item & 7;          // logical 8-elem k-chunk
      const float* src = A + (size_t)(m0 + row) * K_DIM + k0 + sub * 8;
      f32x4 v0 = *(const f32x4*)src;
      f32x4 v1 = *(const f32x4*)(src + 4);
      uint4 o;
      o.x = pack_bf16x2(v0.x, v0.y);
      o.y = pack_bf16x2(v0.z, v0.w);
      o.z = pack_bf16x2(v1.x, v1.y);
      o.w = pack_bf16x2(v1.z, v1.w);
      int chunk = sub ^ (row & 7);
      *(uint4*)&Asm[row * 64 + chunk * 8] = o;
    }
    // -- stage B: global_load_lds x4 per wave, linear LDS dest, pre-swizzled src --
#pragma unroll
    for (int j = 0; j < 4; ++j) {
      int chunkid = w * 4 + j;             // 16 x 1KiB chunks
      int item = chunkid * 64 + lane;
      int row = item >> 3;
      int c = item & 7;
      int sub = c ^ (row & 7);             // inverse swizzle on the SOURCE
      const unsigned short* gp = B + (size_t)(n0 + row) * K_DIM + k0 + sub * 8;
      __builtin_amdgcn_global_load_lds(
          (const __attribute__((address_space(1))) void*)gp,
          (__attribute__((address_space(3))) void*)&Bsm[chunkid * 512],
          16, 0, 0);
    }
    __syncthreads();
    // -- compute: 2 k-subs of 32, 16 MFMA each per wave --
#pragma unroll
    for (int ks = 0; ks < 2; ++ks) {
      const int sub = ks * 4 + g;
      short8 af[4], bfr[4];
#pragma unroll
      for (int a = 0; a < 4; ++a) {
        int row = wm * 64 + a * 16 + c16;
        af[a] = *(const short8*)&Asm[row * 64 + ((sub ^ (row & 7)) * 8)];
      }
#pragma unroll
      for (int b = 0; b < 4; ++b) {
        int row = wn * 64 + b * 16 + c16;
        bfr[b] = *(const short8*)&Bsm[row * 64 + ((sub ^ (row & 7)) * 8)];
      }
#pragma unroll
      for (int a = 0; a < 4; ++a)
#pragma unroll
        for (int b = 0; b < 4; ++b)
          acc[a][b] = __builtin_amdgcn_mfma_f32_16x16x32_bf16(
              af[a], bfr[b], acc[a][b], 0, 0, 0);
    }
    __syncthreads();
  }

  // -- epilogue: tanh(acc + pdec) . wout, reduce over cols, atomicAdd per row --
#pragma unroll
  for (int a = 0; a < 4; ++a) {
    float psum[4] = {0.f, 0.f, 0.f, 0.f};
#pragma unroll
    for (int b = 0; b < 4; ++b) {
      const int col = n0 + wn * 64 + b * 16 + c16;
      const float wo = wout[col];
#pragma unroll
      for (int j = 0; j < 4; ++j) {
        const int rl = wm * 64 + a * 16 + g * 4 + j;  // C/D: col=lane&15, row=(lane>>4)*4+j
        const int bidx = rl & 31;                     // m0 is a multiple of 32
        float v = acc[a][b][j] + pdec[bidx * N_DIM + col];
        psum[j] = fmaf(tanh_fast(v), wo, psum[j]);
      }
    }
#pragma unroll
    for (int j = 0; j < 4; ++j) {
      float p = psum[j];
      p += __shfl_xor(p, 1);
      p += __shfl_xor(p, 2);
      p += __shfl_xor(p, 4);
      p += __shfl_xor(p, 8);
      if (c16 == 0)
        atomicAdd(&logits[m0 + wm * 64 + a * 16 + g * 4 + j], p);
    }
  }
}

// ---- masked softmax over s per batch column; mask dtype auto-detected ----
__global__ void k_softmax(const float* __restrict__ logits,
                          const void* __restrict__ maskp,
                          float* __restrict__ weights) {
  const int b = blockIdx.x;
  const int t = threadIdx.x;
  const int lane = t & 63, wid = t >> 6;
  __shared__ float red[8];
  __shared__ int modeflags[2];

  if (t < 2) modeflags[t] = 0;
  __syncthreads();
  unsigned int w0 = ((const unsigned int*)maskp)[t];  // first 256 words
  if (w0 == 0x3f800000u) modeflags[1] = 1;            // f32 mask
  else if (w0 > 1u) modeflags[0] = 1;                 // byte-packed bools
  __syncthreads();
  const int mode = modeflags[1] ? 2 : (modeflags[0] ? 1 : 0);

  float v[8];
  float mx = -3.0e38f;
#pragma unroll
  for (int i = 0; i < 8; ++i) {
    int idx = (t + i * 256) * BATCH + b;
    float l = logits[idx];
    int mk;
    if (mode == 0) mk = ((const int*)maskp)[idx];
    else if (mode == 1) mk = ((const unsigned char*)maskp)[idx];
    else mk = (((const float*)maskp)[idx] != 0.f);
    l = mk ? l : -2.0e9f;
    v[i] = l;
    mx = fmaxf(mx, l);
  }
#pragma unroll
  for (int off = 1; off < 64; off <<= 1) mx = fmaxf(mx, __shfl_xor(mx, off));
  if (lane == 0) red[wid] = mx;
  __syncthreads();
  mx = fmaxf(fmaxf(red[0], red[1]), fmaxf(red[2], red[3]));

  float sum = 0.f;
#pragma unroll
  for (int i = 0; i < 8; ++i) {
    float e = __expf(v[i] - mx);
    v[i] = e;
    sum += e;
  }
#pragma unroll
  for (int off = 1; off < 64; off <<= 1) sum += __shfl_xor(sum, off);
  if (lane == 0) red[4 + wid] = sum;
  __syncthreads();
  sum = red[4] + red[5] + red[6] + red[7];
  float inv = 1.0f / sum;
#pragma unroll
  for (int i = 0; i < 8; ++i)
    weights[(t + i * 256) * BATCH + b] = v[i] * inv;
}

// ---- attn_response[b][e] = sum_s w[s][b] * enc[s][b][e] ----
__global__ void k_response(const float* __restrict__ enc,
                           const float* __restrict__ weights,
                           float* __restrict__ out) {
  const int b = blockIdx.x & 31;
  const int ch = blockIdx.x >> 5;          // 16 s-chunks of 128
  const int e = threadIdx.x * 4;
  float a0 = 0.f, a1 = 0.f, a2 = 0.f, a3 = 0.f;
  const int s0 = ch * (N_ENC / 16);
  for (int s = s0; s < s0 + N_ENC / 16; ++s) {
    float wv = weights[s * BATCH + b];
    f32x4 x = *(const f32x4*)(enc + ((size_t)s * BATCH + b) * K_DIM + e);
    a0 = fmaf(wv, x.x, a0);
    a1 = fmaf(wv, x.y, a1);
    a2 = fmaf(wv, x.z, a2);
    a3 = fmaf(wv, x.w, a3);
  }
  atomicAdd(&out[b * K_DIM + e + 0], a0);
  atomicAdd(&out[b * K_DIM + e + 1], a1);
  atomicAdd(&out[b * K_DIM + e + 2], a2);
  atomicAdd(&out[b * K_DIM + e + 3], a3);
}

extern "C" void kernel_launch(void* const* d_in, const int* in_sizes, int n_in,
                              void* d_out, int out_size, void* d_ws, size_t ws_size,
                              hipStream_t stream) {
  const float* enc   = (const float*)d_in[0];
  const void*  mask  = d_in[1];
  const float* dec   = (const float*)d_in[2];
  const float* w_enc = (const float*)d_in[3];
  const float* w_dec = (const float*)d_in[4];
  const float* w_out = (const float*)d_in[5];

  float* out_resp = (float*)d_out;                 // [32*1024]
  float* out_w    = out_resp + BATCH * K_DIM;      // [2048*32]

  unsigned short* w_enc_bf = (unsigned short*)d_ws;                       // 2 MiB
  float* pdec   = (float*)((char*)d_ws + (size_t)2 * 1024 * 1024);        // 128 KiB
  float* logits = (float*)((char*)d_ws + (size_t)2 * 1024 * 1024 + 128 * 1024); // 256 KiB

  hipMemsetAsync(logits, 0, (size_t)M_TOT * sizeof(float), stream);
  hipMemsetAsync(out_resp, 0, (size_t)BATCH * K_DIM * sizeof(float), stream);

  k_convert_bf16<<<(N_DIM * K_DIM / 8 + 255) / 256, 256, 0, stream>>>(
      w_enc, w_enc_bf, N_DIM * K_DIM / 8);
  k_proj_dec<<<N_DIM / 8, 256, 0, stream>>>(dec, w_dec, pdec);
  k_gemm_fused<<<(M_TOT / BM) * (N_DIM / BN), 256, 0, stream>>>(
      enc, w_enc_bf, pdec, w_out, logits);
  k_softmax<<<BATCH, 256, 0, stream>>>(logits, mask, out_w);
  k_response<<<BATCH * 16, 256, 0, stream>>>(enc, out_w, out_resp);
}

// Round 2
// 416.170 us; speedup vs baseline: 1.0863x; 1.0863x over previous
//
#include <hip/hip_runtime.h>
#include <hip/hip_bf16.h>
#include <stdint.h>

#define N_ENC 2048
#define BATCH 32
#define M_TOT (N_ENC * BATCH)   // 65536 rows (s*32+b)
#define K_DIM 1024
#define N_DIM 1024
#define BM 128
#define BN 128
#define BK 64

typedef __attribute__((ext_vector_type(4))) float f32x4;
typedef __attribute__((ext_vector_type(8))) short short8;

__device__ __forceinline__ unsigned int pack_bf16x2(float lo, float hi) {
  unsigned int a = __float_as_uint(lo);
  unsigned int b = __float_as_uint(hi);
  a = (a + 0x7fffu + ((a >> 16) & 1u)) >> 16;          // RNE to bf16, low half
  b = (b + 0x7fffu + ((b >> 16) & 1u)) & 0xffff0000u;  // RNE to bf16, high half
  return a | b;
}

__device__ __forceinline__ float tanh_fast(float x) {
  float e = __expf(2.0f * x);
  return 1.0f - 2.0f / (e + 1.0f);
}

// ---- f32 -> bf16 bulk convert (8 elems/thread) ----
__global__ void k_convert_bf16(const float* __restrict__ src,
                               unsigned short* __restrict__ dst, int n8) {
  int i = blockIdx.x * 256 + threadIdx.x;
  if (i >= n8) return;
  const float* p = src + (size_t)i * 8;
  f32x4 v0 = *(const f32x4*)p;
  f32x4 v1 = *(const f32x4*)(p + 4);
  uint4 o;
  o.x = pack_bf16x2(v0.x, v0.y);
  o.y = pack_bf16x2(v0.z, v0.w);
  o.z = pack_bf16x2(v1.x, v1.y);
  o.w = pack_bf16x2(v1.z, v1.w);
  *(uint4*)(dst + (size_t)i * 8) = o;
}

// ---- proj_dec[b][h] = sum_d dec[b][d] * w_dec[h][d] ----
__global__ void k_proj_dec(const float* __restrict__ dec,
                           const float* __restrict__ w_dec,
                           float* __restrict__ proj) {
  int t = threadIdx.x;
  int hh = t & 7, b = t >> 3;
  int h = blockIdx.x * 8 + hh;
  const float* wr = w_dec + (size_t)h * K_DIM;
  const float* dr = dec + (size_t)b * K_DIM;
  float acc = 0.f;
  for (int d = 0; d < K_DIM; d += 4) {
    f32x4 wv = *(const f32x4*)(wr + d);
    f32x4 dv = *(const f32x4*)(dr + d);
    acc = fmaf(wv.x, dv.x, acc);
    acc = fmaf(wv.y, dv.y, acc);
    acc = fmaf(wv.z, dv.z, acc);
    acc = fmaf(wv.w, dv.w, acc);
  }
  proj[b * N_DIM + h] = acc;
}

// ---- fused GEMM: logits[m] += sum_h tanh(A[m].Wenc[h] + pdec[m%32][h]) * wout[h] ----
// PRECONV=true: A is bf16, staged via global_load_lds (no staging VALU).
// PRECONV=false: A is f32, reg-staged + converted (fallback if ws too small).
template <bool PRECONV>
__global__ __launch_bounds__(256) void k_gemm_fused(
    const void* __restrict__ Aptr,
    const unsigned short* __restrict__ B,  // w_enc bf16 [1024][1024]
    const float* __restrict__ pdec,        // [32][1024]
    const float* __restrict__ wout,        // [1024]
    float* __restrict__ logits)            // [65536] (pre-zeroed)
{
  __shared__ __align__(16) unsigned short Asm[BM * BK];  // 16 KiB, XOR-swizzled
  __shared__ __align__(16) unsigned short Bsm[BN * BK];  // 16 KiB, XOR-swizzled

  const int bid = blockIdx.x;
  const int nt = bid & 7;        // n fastest: 8 siblings share an A tile
  const int mt = bid >> 3;
  const int m0 = mt * BM, n0 = nt * BN;
  const int t = threadIdx.x;
  const int lane = t & 63;
  const int w = t >> 6;
  const int wm = w >> 1, wn = w & 1;     // 2x2 waves of 64x64
  const int g = lane >> 4, c16 = lane & 15;

  const f32x4 zero = {0.f, 0.f, 0.f, 0.f};
  f32x4 acc[4][4];
#pragma unroll
  for (int a = 0; a < 4; ++a)
#pragma unroll
    for (int b = 0; b < 4; ++b) acc[a][b] = zero;

  // per-thread hoisted source pointers for the PRECONV staging path
  const unsigned short* gsrc[8];
  if constexpr (PRECONV) {
    const unsigned short* Abf = (const unsigned short*)Aptr;
#pragma unroll
    for (int j = 0; j < 8; ++j) {
      const int chunkid = w * 8 + j;                 // 0..15 A, 16..31 B
      const int isA = chunkid < 16;
      const int ch = isA ? chunkid : chunkid - 16;
      const int row = ch * 8 + (lane >> 3);
      const int sub = (lane & 7) ^ (row & 7);        // inverse swizzle on SOURCE
      gsrc[j] = (isA ? Abf + (size_t)(m0 + row) * K_DIM
                     : B + (size_t)(n0 + row) * K_DIM) + sub * 8;
    }
  }

  for (int kt = 0; kt < K_DIM / BK; ++kt) {
    const int k0 = kt * BK;
    if constexpr (PRECONV) {
#pragma unroll
      for (int j = 0; j < 8; ++j) {
        const int chunkid = w * 8 + j;
        unsigned short* ldst = (chunkid < 16) ? &Asm[chunkid * 512]
                                              : &Bsm[(chunkid - 16) * 512];
        __builtin_amdgcn_global_load_lds(
            (const __attribute__((address_space(1))) void*)gsrc[j],
            (__attribute__((address_space(3))) void*)ldst, 16, 0, 0);
        gsrc[j] += BK;
      }
    } else {
      const float* A = (const float*)Aptr;
#pragma unroll
      for (int i = 0; i < 4; ++i) {
        int item = i * 256 + t;
        int row = item >> 3;
        int sub = item & 7;
        const float* src = A + (size_t)(m0 + row) * K_DIM + k0 + sub * 8;
        f32x4 v0 = *(const f32x4*)src;
        f32x4 v1 = *(const f32x4*)(src + 4);
        uint4 o;
        o.x = pack_bf16x2(v0.x, v0.y);
        o.y = pack_bf16x2(v0.z, v0.w);
        o.z = pack_bf16x2(v1.x, v1.y);
        o.w = pack_bf16x2(v1.z, v1.w);
        int chunk = sub ^ (row & 7);
        *(uint4*)&Asm[row * 64 + chunk * 8] = o;
      }
#pragma unroll
      for (int j = 0; j < 4; ++j) {
        int chunkid = w * 4 + j;
        int item = chunkid * 64 + lane;
        int row = item >> 3;
        int c = item & 7;
        int sub = c ^ (row & 7);
        const unsigned short* gp = B + (size_t)(n0 + row) * K_DIM + k0 + sub * 8;
        __builtin_amdgcn_global_load_lds(
            (const __attribute__((address_space(1))) void*)gp,
            (__attribute__((address_space(3))) void*)&Bsm[chunkid * 512],
            16, 0, 0);
      }
    }
    __syncthreads();
#pragma unroll
    for (int ks = 0; ks < 2; ++ks) {
      const int sub = ks * 4 + g;
      short8 af[4], bfr[4];
#pragma unroll
      for (int a = 0; a < 4; ++a) {
        int row = wm * 64 + a * 16 + c16;
        af[a] = *(const short8*)&Asm[row * 64 + ((sub ^ (row & 7)) * 8)];
      }
#pragma unroll
      for (int b = 0; b < 4; ++b) {
        int row = wn * 64 + b * 16 + c16;
        bfr[b] = *(const short8*)&Bsm[row * 64 + ((sub ^ (row & 7)) * 8)];
      }
#pragma unroll
      for (int a = 0; a < 4; ++a)
#pragma unroll
        for (int b = 0; b < 4; ++b)
          acc[a][b] = __builtin_amdgcn_mfma_f32_16x16x32_bf16(
              af[a], bfr[b], acc[a][b], 0, 0, 0);
    }
    __syncthreads();
  }

  // -- epilogue: tanh(acc + pdec) . wout, reduce over 16 cols, atomicAdd per row --
#pragma unroll
  for (int a = 0; a < 4; ++a) {
    float psum[4] = {0.f, 0.f, 0.f, 0.f};
#pragma unroll
    for (int b = 0; b < 4; ++b) {
      const int col = n0 + wn * 64 + b * 16 + c16;
      const float wo = wout[col];
#pragma unroll
      for (int j = 0; j < 4; ++j) {
        const int rl = wm * 64 + a * 16 + g * 4 + j;  // C/D: col=lane&15, row=(lane>>4)*4+j
        const int bidx = rl & 31;                     // m0 is a multiple of 32
        float v = acc[a][b][j] + pdec[bidx * N_DIM + col];
        psum[j] = fmaf(tanh_fast(v), wo, psum[j]);
      }
    }
#pragma unroll
    for (int j = 0; j < 4; ++j) {
      float p = psum[j];
      p += __shfl_xor(p, 1);
      p += __shfl_xor(p, 2);
      p += __shfl_xor(p, 4);
      p += __shfl_xor(p, 8);
      if (c16 == 0)
        atomicAdd(&logits[m0 + wm * 64 + a * 16 + g * 4 + j], p);
    }
  }
}

// ---- masked softmax over s per batch column; mask dtype auto-detected ----
__global__ void k_softmax(const float* __restrict__ logits,
                          const void* __restrict__ maskp,
                          float* __restrict__ weights) {
  const int b = blockIdx.x;
  const int t = threadIdx.x;
  const int lane = t & 63, wid = t >> 6;
  __shared__ float red[8];
  __shared__ int modeflags[2];

  if (t < 2) modeflags[t] = 0;
  __syncthreads();
  unsigned int w0 = ((const unsigned int*)maskp)[t];
  if (w0 == 0x3f800000u) modeflags[1] = 1;
  else if (w0 > 1u) modeflags[0] = 1;
  __syncthreads();
  const int mode = modeflags[1] ? 2 : (modeflags[0] ? 1 : 0);

  float v[8];
  float mx = -3.0e38f;
#pragma unroll
  for (int i = 0; i < 8; ++i) {
    int idx = (t + i * 256) * BATCH + b;
    float l = logits[idx];
    int mk;
    if (mode == 0) mk = ((const int*)maskp)[idx];
    else if (mode == 1) mk = ((const unsigned char*)maskp)[idx];
    else mk = (((const float*)maskp)[idx] != 0.f);
    l = mk ? l : -2.0e9f;
    v[i] = l;
    mx = fmaxf(mx, l);
  }
#pragma unroll
  for (int off = 1; off < 64; off <<= 1) mx = fmaxf(mx, __shfl_xor(mx, off));
  if (lane == 0) red[wid] = mx;
  __syncthreads();
  mx = fmaxf(fmaxf(red[0], red[1]), fmaxf(red[2], red[3]));

  float sum = 0.f;
#pragma unroll
  for (int i = 0; i < 8; ++i) {
    float e = __expf(v[i] - mx);
    v[i] = e;
    sum += e;
  }
#pragma unroll
  for (int off = 1; off < 64; off <<= 1) sum += __shfl_xor(sum, off);
  if (lane == 0) red[4 + wid] = sum;
  __syncthreads();
  sum = red[4] + red[5] + red[6] + red[7];
  float inv = 1.0f / sum;
#pragma unroll
  for (int i = 0; i < 8; ++i)
    weights[(t + i * 256) * BATCH + b] = v[i] * inv;
}

// ---- attn_response[b][e] = sum_s w[s][b] * enc[s][b][e] ----
__global__ void k_response(const float* __restrict__ enc,
                           const float* __restrict__ weights,
                           float* __restrict__ out) {
  const int b = blockIdx.x & 31;
  const int ch = blockIdx.x >> 5;          // 16 s-chunks of 128
  const int e = threadIdx.x * 4;
  float a0 = 0.f, a1 = 0.f, a2 = 0.f, a3 = 0.f;
  const int s0 = ch * (N_ENC / 16);
  for (int s = s0; s < s0 + N_ENC / 16; ++s) {
    float wv = weights[s * BATCH + b];
    f32x4 x = *(const f32x4*)(enc + ((size_t)s * BATCH + b) * K_DIM + e);
    a0 = fmaf(wv, x.x, a0);
    a1 = fmaf(wv, x.y, a1);
    a2 = fmaf(wv, x.z, a2);
    a3 = fmaf(wv, x.w, a3);
  }
  atomicAdd(&out[b * K_DIM + e + 0], a0);
  atomicAdd(&out[b * K_DIM + e + 1], a1);
  atomicAdd(&out[b * K_DIM + e + 2], a2);
  atomicAdd(&out[b * K_DIM + e + 3], a3);
}

extern "C" void kernel_launch(void* const* d_in, const int* in_sizes, int n_in,
                              void* d_out, int out_size, void* d_ws, size_t ws_size,
                              hipStream_t stream) {
  const float* enc   = (const float*)d_in[0];
  const void*  mask  = d_in[1];
  const float* dec   = (const float*)d_in[2];
  const float* w_enc = (const float*)d_in[3];
  const float* w_dec = (const float*)d_in[4];
  const float* w_out = (const float*)d_in[5];

  float* out_resp = (float*)d_out;                 // [32*1024]
  float* out_w    = out_resp + BATCH * K_DIM;      // [2048*32]

  const size_t enc_bf_bytes = (size_t)M_TOT * K_DIM * 2;       // 128 MiB
  const size_t need = enc_bf_bytes + 2 * 1024 * 1024 + 128 * 1024 + 256 * 1024;
  const bool pre = ws_size >= need;

  char* wsB = (char*)d_ws;
  unsigned short* enc_bf   = (unsigned short*)wsB;             // [65536][1024] bf16
  size_t off = pre ? enc_bf_bytes : 0;
  unsigned short* w_enc_bf = (unsigned short*)(wsB + off);     off += 2 * 1024 * 1024;
  float* pdec   = (float*)(wsB + off);                         off += 128 * 1024;
  float* logits = (float*)(wsB + off);

  hipMemsetAsync(logits, 0, (size_t)M_TOT * sizeof(float), stream);
  hipMemsetAsync(out_resp, 0, (size_t)BATCH * K_DIM * sizeof(float), stream);

  k_convert_bf16<<<(N_DIM * K_DIM / 8 + 255) / 256, 256, 0, stream>>>(
      w_enc, w_enc_bf, N_DIM * K_DIM / 8);
  k_proj_dec<<<N_DIM / 8, 256, 0, stream>>>(dec, w_dec, pdec);

  if (pre) {
    k_convert_bf16<<<(M_TOT * (K_DIM / 8) + 255) / 256, 256, 0, stream>>>(
        enc, enc_bf, M_TOT * (K_DIM / 8));
    k_gemm_fused<true><<<(M_TOT / BM) * (N_DIM / BN), 256, 0, stream>>>(
        (const void*)enc_bf, w_enc_bf, pdec, w_out, logits);
  } else {
    k_gemm_fused<false><<<(M_TOT / BM) * (N_DIM / BN), 256, 0, stream>>>(
        (const void*)enc, w_enc_bf, pdec, w_out, logits);
  }

  k_softmax<<<BATCH, 256, 0, stream>>>(logits, mask, out_w);
  k_response<<<BATCH * 16, 256, 0, stream>>>(enc, out_w, out_resp);
}

// Round 3
// 353.796 us; speedup vs baseline: 1.2778x; 1.1763x over previous
//
#include <hip/hip_runtime.h>
#include <hip/hip_bf16.h>
#include <stdint.h>

#define N_ENC 2048
#define BATCH 32
#define M_TOT (N_ENC * BATCH)   // 65536 rows (s*32+b)
#define K_DIM 1024
#define N_DIM 1024
#define BM 128
#define BN 128
#define BK 64
#define NT (K_DIM / BK)          // 16 K-tiles

typedef __attribute__((ext_vector_type(4))) float f32x4;
typedef __attribute__((ext_vector_type(8))) short short8;

__device__ __forceinline__ unsigned int pack_bf16x2(float lo, float hi) {
  unsigned int a = __float_as_uint(lo);
  unsigned int b = __float_as_uint(hi);
  a = (a + 0x7fffu + ((a >> 16) & 1u)) >> 16;          // RNE to bf16, low half
  b = (b + 0x7fffu + ((b >> 16) & 1u)) & 0xffff0000u;  // RNE to bf16, high half
  return a | b;
}

__device__ __forceinline__ float bf2f(unsigned short u) {
  return __uint_as_float((unsigned int)u << 16);
}

__device__ __forceinline__ float tanh_fast(float x) {
  float e = __expf(2.0f * x);
  return 1.0f - 2.0f / (e + 1.0f);
}

// ---- f32 -> bf16 bulk convert (8 elems/thread) ----
__global__ void k_convert_bf16(const float* __restrict__ src,
                               unsigned short* __restrict__ dst, int n8) {
  int i = blockIdx.x * 256 + threadIdx.x;
  if (i >= n8) return;
  const float* p = src + (size_t)i * 8;
  f32x4 v0 = *(const f32x4*)p;
  f32x4 v1 = *(const f32x4*)(p + 4);
  uint4 o;
  o.x = pack_bf16x2(v0.x, v0.y);
  o.y = pack_bf16x2(v0.z, v0.w);
  o.z = pack_bf16x2(v1.x, v1.y);
  o.w = pack_bf16x2(v1.z, v1.w);
  *(uint4*)(dst + (size_t)i * 8) = o;
}

// ---- proj_dec[b][h] = sum_d dec[b][d] * w_dec[h][d] ----
__global__ void k_proj_dec(const float* __restrict__ dec,
                           const float* __restrict__ w_dec,
                           float* __restrict__ proj) {
  int t = threadIdx.x;
  int hh = t & 7, b = t >> 3;
  int h = blockIdx.x * 8 + hh;
  const float* wr = w_dec + (size_t)h * K_DIM;
  const float* dr = dec + (size_t)b * K_DIM;
  float acc = 0.f;
  for (int d = 0; d < K_DIM; d += 4) {
    f32x4 wv = *(const f32x4*)(wr + d);
    f32x4 dv = *(const f32x4*)(dr + d);
    acc = fmaf(wv.x, dv.x, acc);
    acc = fmaf(wv.y, dv.y, acc);
    acc = fmaf(wv.z, dv.z, acc);
    acc = fmaf(wv.w, dv.w, acc);
  }
  proj[b * N_DIM + h] = acc;
}

// ---- fused GEMM: logits[m] += sum_h tanh(A[m].Wenc[h] + pdec[m%32][h]) * wout[h] ----
// PRECONV=true: bf16 A, counted-vmcnt double-buffered pipeline + XCD swizzle.
// PRECONV=false: f32 A reg-staged fallback (old structure).
template <bool PRECONV>
__global__ __launch_bounds__(256) void k_gemm_fused(
    const void* __restrict__ Aptr,
    const unsigned short* __restrict__ B,  // w_enc bf16 [1024][1024]
    const float* __restrict__ pdec,        // [32][1024]
    const float* __restrict__ wout,        // [1024]
    float* __restrict__ logits)            // [65536] (pre-zeroed)
{
  __shared__ __align__(16) unsigned short Asm[2][BM * BK];  // 2 x 16 KiB, XOR-swizzled
  __shared__ __align__(16) unsigned short Bsm[2][BN * BK];  // 2 x 16 KiB, XOR-swizzled

  // XCD-aware bijective swizzle: 8 n-siblings of one A-tile -> same XCD.
  int bid;
  if constexpr (PRECONV) {
    const int nwg = (M_TOT / BM) * (N_DIM / BN);   // 4096, %8==0
    const int cpx = nwg / 8;
    bid = (blockIdx.x % 8) * cpx + blockIdx.x / 8;
  } else {
    bid = blockIdx.x;
  }
  const int nt = bid & 7;        // n fastest: 8 siblings share an A tile
  const int mt = bid >> 3;
  const int m0 = mt * BM, n0 = nt * BN;
  const int t = threadIdx.x;
  const int lane = t & 63;
  const int w = t >> 6;
  const int wm = w >> 1, wn = w & 1;     // 2x2 waves of 64x64
  const int g = lane >> 4, c16 = lane & 15;

  const f32x4 zero = {0.f, 0.f, 0.f, 0.f};
  f32x4 acc[4][4];
#pragma unroll
  for (int a = 0; a < 4; ++a)
#pragma unroll
    for (int b = 0; b < 4; ++b) acc[a][b] = zero;

#define COMPUTE_TILE(BSEL)                                                     \
  {                                                                            \
    _Pragma("unroll")                                                          \
    for (int ks = 0; ks < 2; ++ks) {                                           \
      const int sub = ks * 4 + g;                                              \
      short8 af[4], bfr[4];                                                    \
      _Pragma("unroll")                                                        \
      for (int a = 0; a < 4; ++a) {                                            \
        int row = wm * 64 + a * 16 + c16;                                      \
        af[a] = *(const short8*)&Asm[BSEL][row * 64 + ((sub ^ (row & 7)) * 8)];\
      }                                                                        \
      _Pragma("unroll")                                                        \
      for (int b = 0; b < 4; ++b) {                                            \
        int row = wn * 64 + b * 16 + c16;                                      \
        bfr[b] = *(const short8*)&Bsm[BSEL][row * 64 + ((sub ^ (row & 7)) * 8)];\
      }                                                                        \
      __builtin_amdgcn_s_setprio(1);                                           \
      _Pragma("unroll")                                                        \
      for (int a = 0; a < 4; ++a)                                              \
        _Pragma("unroll")                                                      \
        for (int b = 0; b < 4; ++b)                                            \
          acc[a][b] = __builtin_amdgcn_mfma_f32_16x16x32_bf16(                 \
              af[a], bfr[b], acc[a][b], 0, 0, 0);                              \
      __builtin_amdgcn_s_setprio(0);                                           \
    }                                                                          \
  }

  if constexpr (PRECONV) {
    const unsigned short* Abf = (const unsigned short*)Aptr;
    // per-thread source pointers, hoisted; bumped by BK per staged tile
    const unsigned short* gsrc[8];
#pragma unroll
    for (int j = 0; j < 8; ++j) {
      const int chunkid = w * 8 + j;                 // 0..15 A, 16..31 B
      const int isA = chunkid < 16;
      const int ch = isA ? chunkid : chunkid - 16;
      const int row = ch * 8 + (lane >> 3);
      const int sub = (lane & 7) ^ (row & 7);        // inverse swizzle on SOURCE
      gsrc[j] = (isA ? Abf + (size_t)(m0 + row) * K_DIM
                     : B + (size_t)(n0 + row) * K_DIM) + sub * 8;
    }

#define STAGE_TILE(BSEL)                                                       \
  {                                                                            \
    _Pragma("unroll")                                                          \
    for (int j = 0; j < 8; ++j) {                                              \
      const int chunkid = w * 8 + j;                                           \
      unsigned short* ldst = (chunkid < 16)                                    \
                                 ? &Asm[BSEL][chunkid * 512]                   \
                                 : &Bsm[BSEL][(chunkid - 16) * 512];           \
      __builtin_amdgcn_global_load_lds(                                        \
          (const __attribute__((address_space(1))) void*)gsrc[j],              \
          (__attribute__((address_space(3))) void*)ldst, 16, 0, 0);            \
      gsrc[j] += BK;                                                           \
    }                                                                          \
  }

    // prologue: T0 -> buf0, T1 -> buf1 (16 loads in flight)
    STAGE_TILE(0);
    STAGE_TILE(1);

    for (int kt = 0; kt < NT - 1; ++kt) {
      // wait: all loads except T_{kt+1}'s 8 have landed => T_kt complete
      asm volatile("s_waitcnt vmcnt(8)" ::: "memory");
      __builtin_amdgcn_sched_barrier(0);
      __builtin_amdgcn_s_barrier();          // all waves' T_kt landed
      const int bsel = kt & 1;
      COMPUTE_TILE(bsel);
      __builtin_amdgcn_s_barrier();          // all waves done reading buf bsel
      if (kt + 2 < NT) STAGE_TILE(bsel);     // refill freed buffer with T_{kt+2}
    }
    // final tile
    asm volatile("s_waitcnt vmcnt(0)" ::: "memory");
    __builtin_amdgcn_sched_barrier(0);
    __builtin_amdgcn_s_barrier();
    COMPUTE_TILE((NT - 1) & 1);
#undef STAGE_TILE
  } else {
    const float* A = (const float*)Aptr;
    for (int kt = 0; kt < NT; ++kt) {
      const int k0 = kt * BK;
#pragma unroll
      for (int i = 0; i < 4; ++i) {
        int item = i * 256 + t;
        int row = item >> 3;
        int sub = item & 7;
        const float* src = A + (size_t)(m0 + row) * K_DIM + k0 + sub * 8;
        f32x4 v0 = *(const f32x4*)src;
        f32x4 v1 = *(const f32x4*)(src + 4);
        uint4 o;
        o.x = pack_bf16x2(v0.x, v0.y);
        o.y = pack_bf16x2(v0.z, v0.w);
        o.z = pack_bf16x2(v1.x, v1.y);
        o.w = pack_bf16x2(v1.z, v1.w);
        int chunk = sub ^ (row & 7);
        *(uint4*)&Asm[0][row * 64 + chunk * 8] = o;
      }
#pragma unroll
      for (int j = 0; j < 4; ++j) {
        int chunkid = w * 4 + j;
        int item = chunkid * 64 + lane;
        int row = item >> 3;
        int c = item & 7;
        int sub = c ^ (row & 7);
        const unsigned short* gp = B + (size_t)(n0 + row) * K_DIM + k0 + sub * 8;
        __builtin_amdgcn_global_load_lds(
            (const __attribute__((address_space(1))) void*)gp,
            (__attribute__((address_space(3))) void*)&Bsm[0][chunkid * 512],
            16, 0, 0);
      }
      __syncthreads();
      COMPUTE_TILE(0);
      __syncthreads();
    }
  }
#undef COMPUTE_TILE

  // -- epilogue: tanh(acc + pdec) . wout, reduce over 16 cols, atomicAdd per row --
#pragma unroll
  for (int a = 0; a < 4; ++a) {
    float psum[4] = {0.f, 0.f, 0.f, 0.f};
#pragma unroll
    for (int b = 0; b < 4; ++b) {
      const int col = n0 + wn * 64 + b * 16 + c16;
      const float wo = wout[col];
#pragma unroll
      for (int j = 0; j < 4; ++j) {
        const int rl = wm * 64 + a * 16 + g * 4 + j;  // C/D: col=lane&15, row=(lane>>4)*4+j
        const int bidx = rl & 31;                     // m0 is a multiple of 32
        float v = acc[a][b][j] + pdec[bidx * N_DIM + col];
        psum[j] = fmaf(tanh_fast(v), wo, psum[j]);
      }
    }
#pragma unroll
    for (int j = 0; j < 4; ++j) {
      float p = psum[j];
      p += __shfl_xor(p, 1);
      p += __shfl_xor(p, 2);
      p += __shfl_xor(p, 4);
      p += __shfl_xor(p, 8);
      if (c16 == 0)
        atomicAdd(&logits[m0 + wm * 64 + a * 16 + g * 4 + j], p);
    }
  }
}

// ---- masked softmax over s per batch column; mask dtype auto-detected ----
__global__ void k_softmax(const float* __restrict__ logits,
                          const void* __restrict__ maskp,
                          float* __restrict__ weights) {
  const int b = blockIdx.x;
  const int t = threadIdx.x;
  const int lane = t & 63, wid = t >> 6;
  __shared__ float red[8];
  __shared__ int modeflags[2];

  if (t < 2) modeflags[t] = 0;
  __syncthreads();
  unsigned int w0 = ((const unsigned int*)maskp)[t];
  if (w0 == 0x3f800000u) modeflags[1] = 1;
  else if (w0 > 1u) modeflags[0] = 1;
  __syncthreads();
  const int mode = modeflags[1] ? 2 : (modeflags[0] ? 1 : 0);

  float v[8];
  float mx = -3.0e38f;
#pragma unroll
  for (int i = 0; i < 8; ++i) {
    int idx = (t + i * 256) * BATCH + b;
    float l = logits[idx];
    int mk;
    if (mode == 0) mk = ((const int*)maskp)[idx];
    else if (mode == 1) mk = ((const unsigned char*)maskp)[idx];
    else mk = (((const float*)maskp)[idx] != 0.f);
    l = mk ? l : -2.0e9f;
    v[i] = l;
    mx = fmaxf(mx, l);
  }
#pragma unroll
  for (int off = 1; off < 64; off <<= 1) mx = fmaxf(mx, __shfl_xor(mx, off));
  if (lane == 0) red[wid] = mx;
  __syncthreads();
  mx = fmaxf(fmaxf(red[0], red[1]), fmaxf(red[2], red[3]));

  float sum = 0.f;
#pragma unroll
  for (int i = 0; i < 8; ++i) {
    float e = __expf(v[i] - mx);
    v[i] = e;
    sum += e;
  }
#pragma unroll
  for (int off = 1; off < 64; off <<= 1) sum += __shfl_xor(sum, off);
  if (lane == 0) red[4 + wid] = sum;
  __syncthreads();
  sum = red[4] + red[5] + red[6] + red[7];
  float inv = 1.0f / sum;
#pragma unroll
  for (int i = 0; i < 8; ++i)
    weights[(t + i * 256) * BATCH + b] = v[i] * inv;
}

// ---- attn_response[b][e] = sum_s w[s][b] * enc_bf[s][b][e]  (bf16 enc) ----
__global__ void k_response_bf(const unsigned short* __restrict__ enc_bf,
                              const float* __restrict__ weights,
                              float* __restrict__ out) {
  const int b = blockIdx.x & 31;
  const int ch = blockIdx.x >> 5;          // 16 s-chunks of 128
  const int e = threadIdx.x * 4;
  float a0 = 0.f, a1 = 0.f, a2 = 0.f, a3 = 0.f;
  const int s0 = ch * (N_ENC / 16);
  for (int s = s0; s < s0 + N_ENC / 16; ++s) {
    float wv = weights[s * BATCH + b];
    ushort4 x = *(const ushort4*)(enc_bf + ((size_t)s * BATCH + b) * K_DIM + e);
    a0 = fmaf(wv, bf2f(x.x), a0);
    a1 = fmaf(wv, bf2f(x.y), a1);
    a2 = fmaf(wv, bf2f(x.z), a2);
    a3 = fmaf(wv, bf2f(x.w), a3);
  }
  atomicAdd(&out[b * K_DIM + e + 0], a0);
  atomicAdd(&out[b * K_DIM + e + 1], a1);
  atomicAdd(&out[b * K_DIM + e + 2], a2);
  atomicAdd(&out[b * K_DIM + e + 3], a3);
}

// ---- f32 fallback response ----
__global__ void k_response(const float* __restrict__ enc,
                           const float* __restrict__ weights,
                           float* __restrict__ out) {
  const int b = blockIdx.x & 31;
  const int ch = blockIdx.x >> 5;
  const int e = threadIdx.x * 4;
  float a0 = 0.f, a1 = 0.f, a2 = 0.f, a3 = 0.f;
  const int s0 = ch * (N_ENC / 16);
  for (int s = s0; s < s0 + N_ENC / 16; ++s) {
    float wv = weights[s * BATCH + b];
    f32x4 x = *(const f32x4*)(enc + ((size_t)s * BATCH + b) * K_DIM + e);
    a0 = fmaf(wv, x.x, a0);
    a1 = fmaf(wv, x.y, a1);
    a2 = fmaf(wv, x.z, a2);
    a3 = fmaf(wv, x.w, a3);
  }
  atomicAdd(&out[b * K_DIM + e + 0], a0);
  atomicAdd(&out[b * K_DIM + e + 1], a1);
  atomicAdd(&out[b * K_DIM + e + 2], a2);
  atomicAdd(&out[b * K_DIM + e + 3], a3);
}

extern "C" void kernel_launch(void* const* d_in, const int* in_sizes, int n_in,
                              void* d_out, int out_size, void* d_ws, size_t ws_size,
                              hipStream_t stream) {
  const float* enc   = (const float*)d_in[0];
  const void*  mask  = d_in[1];
  const float* dec   = (const float*)d_in[2];
  const float* w_enc = (const float*)d_in[3];
  const float* w_dec = (const float*)d_in[4];
  const float* w_out = (const float*)d_in[5];

  float* out_resp = (float*)d_out;                 // [32*1024]
  float* out_w    = out_resp + BATCH * K_DIM;      // [2048*32]

  const size_t enc_bf_bytes = (size_t)M_TOT * K_DIM * 2;       // 128 MiB
  const size_t need = enc_bf_bytes + 2 * 1024 * 1024 + 128 * 1024 + 256 * 1024;
  const bool pre = ws_size >= need;

  char* wsB = (char*)d_ws;
  unsigned short* enc_bf   = (unsigned short*)wsB;             // [65536][1024] bf16
  size_t off = pre ? enc_bf_bytes : 0;
  unsigned short* w_enc_bf = (unsigned short*)(wsB + off);     off += 2 * 1024 * 1024;
  float* pdec   = (float*)(wsB + off);                         off += 128 * 1024;
  float* logits = (float*)(wsB + off);

  hipMemsetAsync(logits, 0, (size_t)M_TOT * sizeof(float), stream);
  hipMemsetAsync(out_resp, 0, (size_t)BATCH * K_DIM * sizeof(float), stream);

  k_convert_bf16<<<(N_DIM * K_DIM / 8 + 255) / 256, 256, 0, stream>>>(
      w_enc, w_enc_bf, N_DIM * K_DIM / 8);
  k_proj_dec<<<N_DIM / 8, 256, 0, stream>>>(dec, w_dec, pdec);

  if (pre) {
    k_convert_bf16<<<(M_TOT * (K_DIM / 8) + 255) / 256, 256, 0, stream>>>(
        enc, enc_bf, M_TOT * (K_DIM / 8));
    k_gemm_fused<true><<<(M_TOT / BM) * (N_DIM / BN), 256, 0, stream>>>(
        (const void*)enc_bf, w_enc_bf, pdec, w_out, logits);
  } else {
    k_gemm_fused<false><<<(M_TOT / BM) * (N_DIM / BN), 256, 0, stream>>>(
        (const void*)enc, w_enc_bf, pdec, w_out, logits);
  }

  k_softmax<<<BATCH, 256, 0, stream>>>(logits, mask, out_w);

  if (pre) {
    k_response_bf<<<BATCH * 16, 256, 0, stream>>>(enc_bf, out_w, out_resp);
  } else {
    k_response<<<BATCH * 16, 256, 0, stream>>>(enc, out_w, out_resp);
  }
}